// Round 7
// baseline (902.814 us; speedup 1.0000x reference)
//
#include <hip/hip_runtime.h>
#include <math.h>

#define NN 100000
#define F_IN 128
#define F_OUT 40
#define FH_PAD 64       // fp16 row stride: 64 elems = 128 B
#define BSHIFT 9        // 512 nodes per bucket
#define BSIZE (1 << BSHIFT)
#define NBUCK ((NN + BSIZE - 1) >> BSHIFT)   // 196
#define EPB_A 4096
#define EPB_C 16384
#define HOPNODES 16     // dst nodes per hop block

typedef short bf16x8 __attribute__((ext_vector_type(8)));
typedef float f32x4 __attribute__((ext_vector_type(4)));

__device__ __forceinline__ short f2bf(float f) {
    union { float f; unsigned u; } uf; uf.f = f;
    unsigned r = uf.u + 0x7FFF + ((uf.u >> 16) & 1);   // RNE
    return (short)(r >> 16);
}

__device__ __forceinline__ float2 unpack16(unsigned v) {
    union { unsigned u; _Float16 h[2]; } c; c.u = v;
    return make_float2((float)c.h[0], (float)c.h[1]);
}

__device__ __forceinline__ unsigned pack16(float x, float y) {
    union { _Float16 h; unsigned short s; } a, b;
    a.h = (_Float16)x; b.h = (_Float16)y;
    return (unsigned)a.s | ((unsigned)b.s << 16);
}

// ---- phase A: bucket histogram ----
__global__ void bhist_kernel(const int* __restrict__ col, int* __restrict__ bcount, int E) {
    __shared__ int h[NBUCK];
    for (int i = threadIdx.x; i < NBUCK; i += blockDim.x) h[i] = 0;
    __syncthreads();
    int e0 = blockIdx.x * EPB_A;
    int e1 = min(e0 + EPB_A, E);
    for (int e = e0 + threadIdx.x; e < e1; e += blockDim.x)
        atomicAdd(&h[col[e] >> BSHIFT], 1);
    __syncthreads();
    for (int i = threadIdx.x; i < NBUCK; i += blockDim.x)
        if (h[i]) atomicAdd(&bcount[i], h[i]);
}

// ---- phase B: scan bucket counts -> bbase; init bcursor ----
__global__ void bscan_kernel(const int* __restrict__ bcount, int* __restrict__ bbase,
                             int* __restrict__ bcursor) {
    __shared__ int sh[256];
    int i = threadIdx.x;
    int v = (i < NBUCK) ? bcount[i] : 0;
    sh[i] = v;
    __syncthreads();
    for (int off = 1; off < 256; off <<= 1) {
        int t = (i >= off) ? sh[i - off] : 0;
        __syncthreads();
        sh[i] += t;
        __syncthreads();
    }
    if (i < NBUCK) { int b = sh[i] - v; bbase[i] = b; bcursor[i] = b; }
}

// ---- phase C: partition edges; staged packs (c_local<<17)|row ----
__global__ void part_kernel(const int* __restrict__ row, const int* __restrict__ col,
                            int* __restrict__ bcursor, int* __restrict__ staged, int E) {
    __shared__ int h[NBUCK];
    __shared__ int cur[NBUCK];
    for (int i = threadIdx.x; i < NBUCK; i += blockDim.x) h[i] = 0;
    __syncthreads();
    int e0 = blockIdx.x * EPB_C;
    int e1 = min(e0 + EPB_C, E);
    for (int e = e0 + threadIdx.x; e < e1; e += blockDim.x)
        atomicAdd(&h[col[e] >> BSHIFT], 1);
    __syncthreads();
    for (int i = threadIdx.x; i < NBUCK; i += blockDim.x)
        cur[i] = h[i] ? atomicAdd(&bcursor[i], h[i]) : 0;
    __syncthreads();
    for (int e = e0 + threadIdx.x; e < e1; e += blockDim.x) {
        int c = col[e];
        int pos = atomicAdd(&cur[c >> BSHIFT], 1);
        staged[pos] = ((c & (BSIZE - 1)) << 17) | row[e];
    }
}

// ---- phase D: per-bucket fine CSR build; adj packs (dst&15)<<17 | row ----
__global__ void build_kernel(const int* __restrict__ staged, const int* __restrict__ bbase,
                             int* __restrict__ adj, int* __restrict__ offs,
                             int* __restrict__ ends, float* __restrict__ dinv, int N, int E) {
    __shared__ int hist[BSIZE];
    __shared__ int cur[BSIZE];
    int bk = blockIdx.x;
    int node0 = bk << BSHIFT;
    int nn = min(BSIZE, N - node0);
    int ebase = bbase[bk];
    int eend = (bk + 1 < NBUCK) ? bbase[bk + 1] : E;
    for (int i = threadIdx.x; i < BSIZE; i += blockDim.x) hist[i] = 0;
    __syncthreads();
    for (int e = ebase + threadIdx.x; e < eend; e += blockDim.x)
        atomicAdd(&hist[staged[e] >> 17], 1);
    __syncthreads();
    int i = threadIdx.x;
    int v = (i < BSIZE) ? hist[i] : 0;
    for (int off = 1; off < BSIZE; off <<= 1) {
        int t = (i < BSIZE && i >= off) ? hist[i - off] : 0;
        __syncthreads();
        if (i < BSIZE) hist[i] += t;
        __syncthreads();
    }
    if (i < BSIZE) {
        int excl = hist[i] - v;
        cur[i] = excl;
        if (i < nn) {
            offs[node0 + i] = ebase + excl;
            ends[node0 + i] = ebase + excl + v;
            dinv[node0 + i] = rsqrtf((float)v + 1.0f);
        }
    }
    __syncthreads();
    for (int e = ebase + threadIdx.x; e < eend; e += blockDim.x) {
        int s = staged[e];
        int pos = atomicAdd(&cur[s >> 17], 1);
        adj[ebase + pos] = s & 0x1FFFFF;   // (dst&15)<<17 | row
    }
}

// ---- zero the dummy rows xs1[NN], xs2[NN] ----
__global__ void zrow_kernel(_Float16* xs1, _Float16* xs2) {
    int t = threadIdx.x;
    if (t < 32) ((unsigned*)xs1)[(size_t)NN * 32 + t] = 0u;
    else        ((unsigned*)xs2)[(size_t)NN * 32 + (t - 32)] = 0u;
}

// ---- MFMA gemm: xs1[n][j] = (x[n] . W[:,j]) * dinv[n]; fp16 output ----
__global__ void __launch_bounds__(256) gemm_kernel(const float* __restrict__ x,
                                                   const float* __restrict__ w,
                                                   const float* __restrict__ dinv,
                                                   _Float16* __restrict__ xs1, int N) {
    __shared__ bf16x8 shB[3][4][64];
    int t = threadIdx.x;
    for (int idx = t; idx < 3 * 4 * 64; idx += 256) {
        int lane = idx & 63;
        int ks = (idx >> 6) & 3;
        int jt = idx >> 8;
        int j = 16 * jt + (lane & 15);
        int k0 = 32 * ks + 8 * (lane >> 4);
        bf16x8 v;
#pragma unroll
        for (int i = 0; i < 8; ++i)
            v[i] = (j < F_OUT) ? f2bf(w[(k0 + i) * F_OUT + j]) : (short)0;
        shB[jt][ks][lane] = v;
    }
    __syncthreads();
    int wave = t >> 6, lane = t & 63;
    int node0 = blockIdx.x * 64 + wave * 16;
    if (node0 >= N) return;

    const float* xrow = x + (size_t)(node0 + (lane & 15)) * F_IN + 8 * (lane >> 4);
    f32x4 acc0 = {0.f, 0.f, 0.f, 0.f};
    f32x4 acc1 = acc0, acc2 = acc0;
#pragma unroll
    for (int ks = 0; ks < 4; ++ks) {
        float4 lo = *(const float4*)(xrow + 32 * ks);
        float4 hi = *(const float4*)(xrow + 32 * ks + 4);
        bf16x8 a;
        a[0] = f2bf(lo.x); a[1] = f2bf(lo.y); a[2] = f2bf(lo.z); a[3] = f2bf(lo.w);
        a[4] = f2bf(hi.x); a[5] = f2bf(hi.y); a[6] = f2bf(hi.z); a[7] = f2bf(hi.w);
        acc0 = __builtin_amdgcn_mfma_f32_16x16x32_bf16(a, shB[0][ks][lane], acc0, 0, 0, 0);
        acc1 = __builtin_amdgcn_mfma_f32_16x16x32_bf16(a, shB[1][ks][lane], acc1, 0, 0, 0);
        acc2 = __builtin_amdgcn_mfma_f32_16x16x32_bf16(a, shB[2][ks][lane], acc2, 0, 0, 0);
    }
    int colj = lane & 15;
    int rbase = (lane >> 4) * 4;
#pragma unroll
    for (int r = 0; r < 4; ++r) {
        int node = node0 + rbase + r;
        float d = dinv[node];
        _Float16* dst = xs1 + (size_t)node * FH_PAD;
        dst[colj]      = (_Float16)(acc0[r] * d);
        dst[16 + colj] = (_Float16)(acc1[r] * d);
        if (colj < F_OUT - 32) dst[32 + colj] = (_Float16)(acc2[r] * d);
    }
}

// ---- hop core: block = 16 dst nodes, LDS f32 accumulation, dwordx4 gathers ----
// 12 edges per wave load instr (5 lanes x 16B = full 80 B row each).
template <int HOP2>
__global__ void __launch_bounds__(256) hop_kernel(const int* __restrict__ offs,
                                                  const int* __restrict__ ends,
                                                  const int* __restrict__ adj,
                                                  const float* __restrict__ dinv,
                                                  const _Float16* __restrict__ xs,
                                                  _Float16* __restrict__ xs_next,
                                                  const float* __restrict__ bias,
                                                  float* __restrict__ out, int N) {
    __shared__ float acc[17][41];   // 16 real + 1 dummy rows; 41-stride spreads banks
    int t = threadIdx.x;
    int node0 = blockIdx.x * HOPNODES;
    int nn16 = min(HOPNODES, N - node0);
    for (int i = t; i < 17 * 41; i += 256) ((float*)acc)[i] = 0.f;
    __syncthreads();

    int wave = t >> 6, lane = t & 63;
    int slot = lane / 5;            // 0..12 (12 = idle)
    int q = lane - slot * 5;        // 0..4
    int ebeg = offs[node0];
    int eend = ends[node0 + nn16 - 1];
    const char* xsb = (const char*)xs;

    for (int base = ebeg + wave * 60; base < eend; base += 240) {
        int a = -1;
        if (lane < 60 && base + lane < eend) a = adj[base + lane];
#pragma unroll
        for (int j = 0; j < 5; ++j) {
            int ae = __shfl(a, j * 12 + slot);
            int r, dl;
            if (slot < 12 && ae >= 0) { r = ae & 0x1FFFF; dl = (ae >> 17) & 15; }
            else { r = NN; dl = 16; }
            union { uint4 u; _Float16 h[8]; } c;
            c.u = *(const uint4*)(xsb + (((size_t)r) << 7) + (q << 4));
#pragma unroll
            for (int i = 0; i < 8; ++i)
                atomicAdd(&acc[dl][q * 8 + i], (float)c.h[i]);
        }
    }
    __syncthreads();

    // epilogue: wave handles 4 nodes
    float bl = 0.f;
    if (HOP2 && lane < F_OUT) bl = bias[lane];
#pragma unroll
    for (int i = 0; i < 4; ++i) {
        int l = wave * 4 + i;
        if (l >= nn16) break;
        int n = node0 + l;
        if (!HOP2) {
            if (lane < F_OUT / 2) {
                float d = dinv[n];
                float dd = d * d;
                float2 s = unpack16(((const unsigned*)xs)[(size_t)n * 32 + lane]);
                float vx = (acc[l][2 * lane] + s.x) * dd;
                float vy = (acc[l][2 * lane + 1] + s.y) * dd;
                ((unsigned*)xs_next)[(size_t)n * 32 + lane] = pack16(vx, vy);
            }
        } else {
            float logit = 0.f, v = -INFINITY;
            if (lane < F_OUT) {
                float d = dinv[n];
                float s = (float)xs[(size_t)n * FH_PAD + lane];
                logit = (acc[l][lane] + s) * d + bl;
                v = logit;
            }
#pragma unroll
            for (int off = 32; off; off >>= 1) v = fmaxf(v, __shfl_xor(v, off));
            float ex = (lane < F_OUT) ? expf(logit - v) : 0.f;
#pragma unroll
            for (int off = 32; off; off >>= 1) ex += __shfl_xor(ex, off);
            if (lane < F_OUT) out[(size_t)n * F_OUT + lane] = logit - v - logf(ex);
        }
    }
}

extern "C" void kernel_launch(void* const* d_in, const int* in_sizes, int n_in,
                              void* d_out, int out_size, void* d_ws, size_t ws_size,
                              hipStream_t stream) {
    const float* x    = (const float*)d_in[0];
    const int*   eidx = (const int*)d_in[1];
    const float* w    = (const float*)d_in[2];
    const float* bias = (const float*)d_in[3];
    float* out = (float*)d_out;

    const int E = in_sizes[1] / 2;
    const int N = NN;

    char* ws = (char*)d_ws;
    int*      bcount  = (int*)ws;      ws += 256 * 4;
    int*      bbase   = (int*)ws;      ws += 256 * 4;
    int*      bcursor = (int*)ws;      ws += 256 * 4;
    int*      offs    = (int*)ws;      ws += (size_t)N * 4;
    int*      ends    = (int*)ws;      ws += (size_t)N * 4;
    float*    dinv    = (float*)ws;    ws += (size_t)N * 4;
    int*      adj     = (int*)ws;      ws += (size_t)E * 4;
    _Float16* xs1     = (_Float16*)ws; ws += (size_t)(N + 1) * FH_PAD * 2;
    _Float16* xs2     = (_Float16*)ws; ws += (size_t)(N + 1) * FH_PAD * 2;
    int*      staged  = (int*)ws;

    const int* row = eidx;
    const int* col = eidx + E;

    hipMemsetAsync(bcount, 0, NBUCK * sizeof(int), stream);
    bhist_kernel<<<(E + EPB_A - 1) / EPB_A, 1024, 0, stream>>>(col, bcount, E);
    bscan_kernel<<<1, 256, 0, stream>>>(bcount, bbase, bcursor);
    part_kernel<<<(E + EPB_C - 1) / EPB_C, 1024, 0, stream>>>(row, col, bcursor, staged, E);
    build_kernel<<<NBUCK, 1024, 0, stream>>>(staged, bbase, adj, offs, ends, dinv, N, E);

    zrow_kernel<<<1, 64, 0, stream>>>(xs1, xs2);
    gemm_kernel<<<(N + 63) / 64, 256, 0, stream>>>(x, w, dinv, xs1, N);

    int hblocks = (N + HOPNODES - 1) / HOPNODES;
    hop_kernel<0><<<hblocks, 256, 0, stream>>>(offs, ends, adj, dinv, xs1, xs2,
                                               bias, out, N);
    hop_kernel<1><<<hblocks, 256, 0, stream>>>(offs, ends, adj, dinv, xs2, nullptr,
                                               bias, out, N);
}

// Round 8
// 203.825 us; speedup vs baseline: 4.4293x; 4.4293x over previous
//
#include <hip/hip_runtime.h>
#include <math.h>

#define NN 100000
#define F_IN 128
#define F_OUT 40
#define FH_PAD 64       // fp16 row stride: 64 elems = 128 B = 32 dwords
#define BSHIFT 9        // 512 nodes per bucket
#define BSIZE (1 << BSHIFT)
#define NBUCK ((NN + BSIZE - 1) >> BSHIFT)   // 196
#define EPB_A 4096
#define EPB_C 16384

typedef short bf16x8 __attribute__((ext_vector_type(8)));
typedef float f32x4 __attribute__((ext_vector_type(4)));

__device__ __forceinline__ short f2bf(float f) {
    union { float f; unsigned u; } uf; uf.f = f;
    unsigned r = uf.u + 0x7FFF + ((uf.u >> 16) & 1);   // RNE
    return (short)(r >> 16);
}

__device__ __forceinline__ float2 unpack16(unsigned v) {
    union { unsigned u; _Float16 h[2]; } c; c.u = v;
    return make_float2((float)c.h[0], (float)c.h[1]);
}

__device__ __forceinline__ unsigned pack16(float x, float y) {
    union { _Float16 h; unsigned short s; } a, b;
    a.h = (_Float16)x; b.h = (_Float16)y;
    return (unsigned)a.s | ((unsigned)b.s << 16);
}

// f32 acc += f16 (lo or hi half of dword) -- one v_fma_mix_f32 each
#define MIX_LO(acc, d, one) \
    asm("v_fma_mix_f32 %0, %1, %2, %0 op_sel:[0,0,0] op_sel_hi:[1,0,0]" \
        : "+v"(acc) : "v"(d), "v"(one))
#define MIX_HI(acc, d, one) \
    asm("v_fma_mix_f32 %0, %1, %2, %0 op_sel:[1,0,0] op_sel_hi:[1,0,0]" \
        : "+v"(acc) : "v"(d), "v"(one))

// ---- phase A: bucket histogram ----
__global__ void bhist_kernel(const int* __restrict__ col, int* __restrict__ bcount, int E) {
    __shared__ int h[NBUCK];
    for (int i = threadIdx.x; i < NBUCK; i += blockDim.x) h[i] = 0;
    __syncthreads();
    int e0 = blockIdx.x * EPB_A;
    int e1 = min(e0 + EPB_A, E);
    for (int e = e0 + threadIdx.x; e < e1; e += blockDim.x)
        atomicAdd(&h[col[e] >> BSHIFT], 1);
    __syncthreads();
    for (int i = threadIdx.x; i < NBUCK; i += blockDim.x)
        if (h[i]) atomicAdd(&bcount[i], h[i]);
}

// ---- phase B: scan bucket counts -> bbase; init bcursor ----
__global__ void bscan_kernel(const int* __restrict__ bcount, int* __restrict__ bbase,
                             int* __restrict__ bcursor) {
    __shared__ int sh[256];
    int i = threadIdx.x;
    int v = (i < NBUCK) ? bcount[i] : 0;
    sh[i] = v;
    __syncthreads();
    for (int off = 1; off < 256; off <<= 1) {
        int t = (i >= off) ? sh[i - off] : 0;
        __syncthreads();
        sh[i] += t;
        __syncthreads();
    }
    if (i < NBUCK) { int b = sh[i] - v; bbase[i] = b; bcursor[i] = b; }
}

// ---- phase C: partition edges; staged packs (c_local<<17)|row ----
__global__ void part_kernel(const int* __restrict__ row, const int* __restrict__ col,
                            int* __restrict__ bcursor, int* __restrict__ staged, int E) {
    __shared__ int h[NBUCK];
    __shared__ int cur[NBUCK];
    for (int i = threadIdx.x; i < NBUCK; i += blockDim.x) h[i] = 0;
    __syncthreads();
    int e0 = blockIdx.x * EPB_C;
    int e1 = min(e0 + EPB_C, E);
    for (int e = e0 + threadIdx.x; e < e1; e += blockDim.x)
        atomicAdd(&h[col[e] >> BSHIFT], 1);
    __syncthreads();
    for (int i = threadIdx.x; i < NBUCK; i += blockDim.x)
        cur[i] = h[i] ? atomicAdd(&bcursor[i], h[i]) : 0;
    __syncthreads();
    for (int e = e0 + threadIdx.x; e < e1; e += blockDim.x) {
        int c = col[e];
        int pos = atomicAdd(&cur[c >> BSHIFT], 1);
        staged[pos] = ((c & (BSIZE - 1)) << 17) | row[e];
    }
}

// ---- phase D: per-bucket fine CSR build + deg/offs/ends/dinv ----
__global__ void build_kernel(const int* __restrict__ staged, const int* __restrict__ bbase,
                             int* __restrict__ adj, int* __restrict__ offs,
                             int* __restrict__ ends, float* __restrict__ dinv, int N, int E) {
    __shared__ int hist[BSIZE];
    __shared__ int cur[BSIZE];
    int bk = blockIdx.x;
    int node0 = bk << BSHIFT;
    int nn = min(BSIZE, N - node0);
    int ebase = bbase[bk];
    int eend = (bk + 1 < NBUCK) ? bbase[bk + 1] : E;
    for (int i = threadIdx.x; i < BSIZE; i += blockDim.x) hist[i] = 0;
    __syncthreads();
    for (int e = ebase + threadIdx.x; e < eend; e += blockDim.x)
        atomicAdd(&hist[staged[e] >> 17], 1);
    __syncthreads();
    int i = threadIdx.x;
    int v = (i < BSIZE) ? hist[i] : 0;
    for (int off = 1; off < BSIZE; off <<= 1) {
        int t = (i < BSIZE && i >= off) ? hist[i - off] : 0;
        __syncthreads();
        if (i < BSIZE) hist[i] += t;
        __syncthreads();
    }
    if (i < BSIZE) {
        int excl = hist[i] - v;
        cur[i] = excl;
        if (i < nn) {
            offs[node0 + i] = ebase + excl;
            ends[node0 + i] = ebase + excl + v;
            dinv[node0 + i] = rsqrtf((float)v + 1.0f);
        }
    }
    __syncthreads();
    for (int e = ebase + threadIdx.x; e < eend; e += blockDim.x) {
        int s = staged[e];
        int pos = atomicAdd(&cur[s >> 17], 1);
        adj[ebase + pos] = s & 0x1FFFF;
    }
}

// ---- zero the dummy rows xs1[NN], xs2[NN] ----
__global__ void zrow_kernel(_Float16* xs1, _Float16* xs2) {
    int t = threadIdx.x;
    if (t < 32) ((unsigned*)xs1)[(size_t)NN * 32 + t] = 0u;
    else        ((unsigned*)xs2)[(size_t)NN * 32 + (t - 32)] = 0u;
}

// ---- MFMA gemm: xs1[n][j] = (x[n] . W[:,j]) * dinv[n]; fp16 out, full 64-col row ----
__global__ void __launch_bounds__(256) gemm_kernel(const float* __restrict__ x,
                                                   const float* __restrict__ w,
                                                   const float* __restrict__ dinv,
                                                   _Float16* __restrict__ xs1, int N) {
    __shared__ bf16x8 shB[3][4][64];
    int t = threadIdx.x;
    for (int idx = t; idx < 3 * 4 * 64; idx += 256) {
        int lane = idx & 63;
        int ks = (idx >> 6) & 3;
        int jt = idx >> 8;
        int j = 16 * jt + (lane & 15);
        int k0 = 32 * ks + 8 * (lane >> 4);
        bf16x8 v;
#pragma unroll
        for (int i = 0; i < 8; ++i)
            v[i] = (j < F_OUT) ? f2bf(w[(k0 + i) * F_OUT + j]) : (short)0;
        shB[jt][ks][lane] = v;
    }
    __syncthreads();
    int wave = t >> 6, lane = t & 63;
    int node0 = blockIdx.x * 64 + wave * 16;
    if (node0 >= N) return;

    const float* xrow = x + (size_t)(node0 + (lane & 15)) * F_IN + 8 * (lane >> 4);
    f32x4 acc0 = {0.f, 0.f, 0.f, 0.f};
    f32x4 acc1 = acc0, acc2 = acc0;
#pragma unroll
    for (int ks = 0; ks < 4; ++ks) {
        float4 lo = *(const float4*)(xrow + 32 * ks);
        float4 hi = *(const float4*)(xrow + 32 * ks + 4);
        bf16x8 a;
        a[0] = f2bf(lo.x); a[1] = f2bf(lo.y); a[2] = f2bf(lo.z); a[3] = f2bf(lo.w);
        a[4] = f2bf(hi.x); a[5] = f2bf(hi.y); a[6] = f2bf(hi.z); a[7] = f2bf(hi.w);
        acc0 = __builtin_amdgcn_mfma_f32_16x16x32_bf16(a, shB[0][ks][lane], acc0, 0, 0, 0);
        acc1 = __builtin_amdgcn_mfma_f32_16x16x32_bf16(a, shB[1][ks][lane], acc1, 0, 0, 0);
        acc2 = __builtin_amdgcn_mfma_f32_16x16x32_bf16(a, shB[2][ks][lane], acc2, 0, 0, 0);
    }
    int colj = lane & 15;
    int rbase = (lane >> 4) * 4;
#pragma unroll
    for (int r = 0; r < 4; ++r) {
        int node = node0 + rbase + r;
        float d = dinv[node];
        _Float16* dst = xs1 + (size_t)node * FH_PAD;
        dst[colj]      = (_Float16)(acc0[r] * d);
        dst[16 + colj] = (_Float16)(acc1[r] * d);
        dst[32 + colj] = (colj < 8) ? (_Float16)(acc2[r] * d) : (_Float16)0.f;
        dst[48 + colj] = (_Float16)0.f;
    }
}

// ---- hop: wave = 1 dst node; lane = (slot 0..3, c 0..15); 4 edges/iter,
// each edge's full 128 B row loaded by 16 lanes x dwordx2; v_fma_mix accumulate ----
template <int HOP2>
__global__ void __launch_bounds__(256) hop_kernel(const int* __restrict__ offs,
                                                  const int* __restrict__ ends,
                                                  const int* __restrict__ adj,
                                                  const float* __restrict__ dinv,
                                                  const _Float16* __restrict__ xs,
                                                  _Float16* __restrict__ xs_next,
                                                  const float* __restrict__ bias,
                                                  float* __restrict__ out, int N) {
    int t = threadIdx.x;
    int n = blockIdx.x * 4 + (t >> 6);
    if (n >= N) return;
    int lane = t & 63;
    int slot = lane >> 4;     // 0..3: edge slot
    int c = lane & 15;        // dword-pair: cols 4c..4c+3
    int b = offs[n], e = ends[n];

    const unsigned* base = (const unsigned*)xs;   // row = 32 dwords
    float a0 = 0.f, a1 = 0.f, a2 = 0.f, a3 = 0.f;
    float one = 1.0f;

    for (int kb = b; kb < e; kb += 4) {
        int k = kb + slot;
        int ka = (k < e) ? k : b;          // clamp to a valid index (loop => b < e)
        int r0 = adj[ka];
        int r = (k < e) ? r0 : NN;         // OOB slots -> zeroed dummy row
        uint2 dd = *(const uint2*)(base + r * 32 + c * 2);
        MIX_LO(a0, dd.x, one);
        MIX_HI(a1, dd.x, one);
        MIX_LO(a2, dd.y, one);
        MIX_HI(a3, dd.y, one);
    }
    // reduce across the 4 slots
    a0 += __shfl_xor(a0, 16); a1 += __shfl_xor(a1, 16);
    a2 += __shfl_xor(a2, 16); a3 += __shfl_xor(a3, 16);
    a0 += __shfl_xor(a0, 32); a1 += __shfl_xor(a1, 32);
    a2 += __shfl_xor(a2, 32); a3 += __shfl_xor(a3, 32);

    // self term
    uint2 sd = *(const uint2*)(base + n * 32 + c * 2);
    float2 s01 = unpack16(sd.x), s23 = unpack16(sd.y);
    a0 += s01.x; a1 += s01.y; a2 += s23.x; a3 += s23.y;

    if (!HOP2) {
        if (slot == 0) {
            float d = dinv[n];
            float dd = d * d;
            uint2 wv;
            wv.x = pack16(a0 * dd, a1 * dd);
            wv.y = pack16(a2 * dd, a3 * dd);
            *(uint2*)((unsigned*)xs_next + (size_t)n * 32 + c * 2) = wv;
        }
    } else {
        float d = dinv[n];
        float4 bb = {0.f, 0.f, 0.f, 0.f};
        if (c < 10) bb = ((const float4*)bias)[c];
        float l0 = a0 * d + bb.x, l1 = a1 * d + bb.y;
        float l2 = a2 * d + bb.z, l3 = a3 * d + bb.w;
        float vm = fmaxf(fmaxf(l0, l1), fmaxf(l2, l3));
        if (c >= 10) vm = -INFINITY;
#pragma unroll
        for (int off = 1; off < 16; off <<= 1) vm = fmaxf(vm, __shfl_xor(vm, off));
        float ex = 0.f;
        if (c < 10) ex = expf(l0 - vm) + expf(l1 - vm) + expf(l2 - vm) + expf(l3 - vm);
#pragma unroll
        for (int off = 1; off < 16; off <<= 1) ex += __shfl_xor(ex, off);
        if (slot == 0 && c < 10) {
            float ls = vm + logf(ex);
            float4 o = {l0 - ls, l1 - ls, l2 - ls, l3 - ls};
            *(float4*)(out + (size_t)n * F_OUT + 4 * c) = o;
        }
    }
}

extern "C" void kernel_launch(void* const* d_in, const int* in_sizes, int n_in,
                              void* d_out, int out_size, void* d_ws, size_t ws_size,
                              hipStream_t stream) {
    const float* x    = (const float*)d_in[0];
    const int*   eidx = (const int*)d_in[1];
    const float* w    = (const float*)d_in[2];
    const float* bias = (const float*)d_in[3];
    float* out = (float*)d_out;

    const int E = in_sizes[1] / 2;
    const int N = NN;

    char* ws = (char*)d_ws;
    int*      bcount  = (int*)ws;      ws += 256 * 4;
    int*      bbase   = (int*)ws;      ws += 256 * 4;
    int*      bcursor = (int*)ws;      ws += 256 * 4;
    int*      offs    = (int*)ws;      ws += (size_t)N * 4;
    int*      ends    = (int*)ws;      ws += (size_t)N * 4;
    float*    dinv    = (float*)ws;    ws += (size_t)N * 4;
    int*      adj     = (int*)ws;      ws += (size_t)E * 4;
    _Float16* xs1     = (_Float16*)ws; ws += (size_t)(N + 1) * FH_PAD * 2;
    _Float16* xs2     = (_Float16*)ws; ws += (size_t)(N + 1) * FH_PAD * 2;
    int*      staged  = (int*)ws;

    const int* row = eidx;
    const int* col = eidx + E;

    hipMemsetAsync(bcount, 0, NBUCK * sizeof(int), stream);
    zrow_kernel<<<1, 64, 0, stream>>>(xs1, xs2);
    bhist_kernel<<<(E + EPB_A - 1) / EPB_A, 1024, 0, stream>>>(col, bcount, E);
    bscan_kernel<<<1, 256, 0, stream>>>(bcount, bbase, bcursor);
    part_kernel<<<(E + EPB_C - 1) / EPB_C, 1024, 0, stream>>>(row, col, bcursor, staged, E);
    build_kernel<<<NBUCK, 1024, 0, stream>>>(staged, bbase, adj, offs, ends, dinv, N, E);

    gemm_kernel<<<(N + 63) / 64, 256, 0, stream>>>(x, w, dinv, xs1, N);

    hop_kernel<0><<<(N + 3) / 4, 256, 0, stream>>>(offs, ends, adj, dinv, xs1, xs2,
                                                   bias, out, N);
    hop_kernel<1><<<(N + 3) / 4, 256, 0, stream>>>(offs, ends, adj, dinv, xs2, nullptr,
                                                   bias, out, N);
}

// Round 9
// 173.143 us; speedup vs baseline: 5.2143x; 1.1772x over previous
//
#include <hip/hip_runtime.h>
#include <math.h>

#define NN 100000
#define F_IN 128
#define F_OUT 40
#define FH_PAD 64       // fp16 row stride: 64 elems = 128 B = 8 x 16B chunks
#define BSHIFT 9        // 512 nodes per bucket
#define BSIZE (1 << BSHIFT)
#define NBUCK ((NN + BSIZE - 1) >> BSHIFT)   // 196
#define EPB_A 4096
#define EPB_C 16384

typedef short bf16x8 __attribute__((ext_vector_type(8)));
typedef float f32x4 __attribute__((ext_vector_type(4)));

__device__ __forceinline__ short f2bf(float f) {
    union { float f; unsigned u; } uf; uf.f = f;
    unsigned r = uf.u + 0x7FFF + ((uf.u >> 16) & 1);   // RNE
    return (short)(r >> 16);
}

__device__ __forceinline__ float2 unpack16(unsigned v) {
    union { unsigned u; _Float16 h[2]; } c; c.u = v;
    return make_float2((float)c.h[0], (float)c.h[1]);
}

__device__ __forceinline__ unsigned pack16(float x, float y) {
    union { _Float16 h; unsigned short s; } a, b;
    a.h = (_Float16)x; b.h = (_Float16)y;
    return (unsigned)a.s | ((unsigned)b.s << 16);
}

// f32 acc += f16 (lo or hi half of dword) -- one v_fma_mix_f32 each
#define MIX_LO(acc, d, one) \
    asm("v_fma_mix_f32 %0, %1, %2, %0 op_sel:[0,0,0] op_sel_hi:[1,0,0]" \
        : "+v"(acc) : "v"(d), "v"(one))
#define MIX_HI(acc, d, one) \
    asm("v_fma_mix_f32 %0, %1, %2, %0 op_sel:[1,0,0] op_sel_hi:[1,0,0]" \
        : "+v"(acc) : "v"(d), "v"(one))

// ---- phase A: bucket histogram ----
__global__ void bhist_kernel(const int* __restrict__ col, int* __restrict__ bcount, int E) {
    __shared__ int h[NBUCK];
    for (int i = threadIdx.x; i < NBUCK; i += blockDim.x) h[i] = 0;
    __syncthreads();
    int e0 = blockIdx.x * EPB_A;
    int e1 = min(e0 + EPB_A, E);
    for (int e = e0 + threadIdx.x; e < e1; e += blockDim.x)
        atomicAdd(&h[col[e] >> BSHIFT], 1);
    __syncthreads();
    for (int i = threadIdx.x; i < NBUCK; i += blockDim.x)
        if (h[i]) atomicAdd(&bcount[i], h[i]);
}

// ---- phase B: scan bucket counts -> bbase; init bcursor ----
__global__ void bscan_kernel(const int* __restrict__ bcount, int* __restrict__ bbase,
                             int* __restrict__ bcursor) {
    __shared__ int sh[256];
    int i = threadIdx.x;
    int v = (i < NBUCK) ? bcount[i] : 0;
    sh[i] = v;
    __syncthreads();
    for (int off = 1; off < 256; off <<= 1) {
        int t = (i >= off) ? sh[i - off] : 0;
        __syncthreads();
        sh[i] += t;
        __syncthreads();
    }
    if (i < NBUCK) { int b = sh[i] - v; bbase[i] = b; bcursor[i] = b; }
}

// ---- phase C: partition edges; staged packs (c_local<<17)|row ----
__global__ void part_kernel(const int* __restrict__ row, const int* __restrict__ col,
                            int* __restrict__ bcursor, int* __restrict__ staged, int E) {
    __shared__ int h[NBUCK];
    __shared__ int cur[NBUCK];
    for (int i = threadIdx.x; i < NBUCK; i += blockDim.x) h[i] = 0;
    __syncthreads();
    int e0 = blockIdx.x * EPB_C;
    int e1 = min(e0 + EPB_C, E);
    for (int e = e0 + threadIdx.x; e < e1; e += blockDim.x)
        atomicAdd(&h[col[e] >> BSHIFT], 1);
    __syncthreads();
    for (int i = threadIdx.x; i < NBUCK; i += blockDim.x)
        cur[i] = h[i] ? atomicAdd(&bcursor[i], h[i]) : 0;
    __syncthreads();
    for (int e = e0 + threadIdx.x; e < e1; e += blockDim.x) {
        int c = col[e];
        int pos = atomicAdd(&cur[c >> BSHIFT], 1);
        staged[pos] = ((c & (BSIZE - 1)) << 17) | row[e];
    }
}

// ---- phase D: per-bucket fine CSR build + deg/offs/ends/dinv ----
__global__ void build_kernel(const int* __restrict__ staged, const int* __restrict__ bbase,
                             int* __restrict__ adj, int* __restrict__ offs,
                             int* __restrict__ ends, float* __restrict__ dinv, int N, int E) {
    __shared__ int hist[BSIZE];
    __shared__ int cur[BSIZE];
    int bk = blockIdx.x;
    int node0 = bk << BSHIFT;
    int nn = min(BSIZE, N - node0);
    int ebase = bbase[bk];
    int eend = (bk + 1 < NBUCK) ? bbase[bk + 1] : E;
    for (int i = threadIdx.x; i < BSIZE; i += blockDim.x) hist[i] = 0;
    __syncthreads();
    for (int e = ebase + threadIdx.x; e < eend; e += blockDim.x)
        atomicAdd(&hist[staged[e] >> 17], 1);
    __syncthreads();
    int i = threadIdx.x;
    int v = (i < BSIZE) ? hist[i] : 0;
    for (int off = 1; off < BSIZE; off <<= 1) {
        int t = (i < BSIZE && i >= off) ? hist[i - off] : 0;
        __syncthreads();
        if (i < BSIZE) hist[i] += t;
        __syncthreads();
    }
    if (i < BSIZE) {
        int excl = hist[i] - v;
        cur[i] = excl;
        if (i < nn) {
            offs[node0 + i] = ebase + excl;
            ends[node0 + i] = ebase + excl + v;
            dinv[node0 + i] = rsqrtf((float)v + 1.0f);
        }
    }
    __syncthreads();
    for (int e = ebase + threadIdx.x; e < eend; e += blockDim.x) {
        int s = staged[e];
        int pos = atomicAdd(&cur[s >> 17], 1);
        adj[ebase + pos] = s & 0x1FFFF;
    }
}

// ---- zero the dummy rows xs1[NN], xs2[NN] ----
__global__ void zrow_kernel(_Float16* xs1, _Float16* xs2) {
    int t = threadIdx.x;
    if (t < 32) ((unsigned*)xs1)[(size_t)NN * 32 + t] = 0u;
    else        ((unsigned*)xs2)[(size_t)NN * 32 + (t - 32)] = 0u;
}

// ---- MFMA gemm: xs1[n][j] = (x[n] . W[:,j]) * dinv[n]; fp16 out, full 64-col row ----
__global__ void __launch_bounds__(256) gemm_kernel(const float* __restrict__ x,
                                                   const float* __restrict__ w,
                                                   const float* __restrict__ dinv,
                                                   _Float16* __restrict__ xs1, int N) {
    __shared__ bf16x8 shB[3][4][64];
    int t = threadIdx.x;
    for (int idx = t; idx < 3 * 4 * 64; idx += 256) {
        int lane = idx & 63;
        int ks = (idx >> 6) & 3;
        int jt = idx >> 8;
        int j = 16 * jt + (lane & 15);
        int k0 = 32 * ks + 8 * (lane >> 4);
        bf16x8 v;
#pragma unroll
        for (int i = 0; i < 8; ++i)
            v[i] = (j < F_OUT) ? f2bf(w[(k0 + i) * F_OUT + j]) : (short)0;
        shB[jt][ks][lane] = v;
    }
    __syncthreads();
    int wave = t >> 6, lane = t & 63;
    int node0 = blockIdx.x * 64 + wave * 16;
    if (node0 >= N) return;

    const float* xrow = x + (size_t)(node0 + (lane & 15)) * F_IN + 8 * (lane >> 4);
    f32x4 acc0 = {0.f, 0.f, 0.f, 0.f};
    f32x4 acc1 = acc0, acc2 = acc0;
#pragma unroll
    for (int ks = 0; ks < 4; ++ks) {
        float4 lo = *(const float4*)(xrow + 32 * ks);
        float4 hi = *(const float4*)(xrow + 32 * ks + 4);
        bf16x8 a;
        a[0] = f2bf(lo.x); a[1] = f2bf(lo.y); a[2] = f2bf(lo.z); a[3] = f2bf(lo.w);
        a[4] = f2bf(hi.x); a[5] = f2bf(hi.y); a[6] = f2bf(hi.z); a[7] = f2bf(hi.w);
        acc0 = __builtin_amdgcn_mfma_f32_16x16x32_bf16(a, shB[0][ks][lane], acc0, 0, 0, 0);
        acc1 = __builtin_amdgcn_mfma_f32_16x16x32_bf16(a, shB[1][ks][lane], acc1, 0, 0, 0);
        acc2 = __builtin_amdgcn_mfma_f32_16x16x32_bf16(a, shB[2][ks][lane], acc2, 0, 0, 0);
    }
    int colj = lane & 15;
    int rbase = (lane >> 4) * 4;
#pragma unroll
    for (int r = 0; r < 4; ++r) {
        int node = node0 + rbase + r;
        float d = dinv[node];
        _Float16* dst = xs1 + (size_t)node * FH_PAD;
        dst[colj]      = (_Float16)(acc0[r] * d);
        dst[16 + colj] = (_Float16)(acc1[r] * d);
        dst[32 + colj] = (colj < 8) ? (_Float16)(acc2[r] * d) : (_Float16)0.f;
        dst[48 + colj] = (_Float16)0.f;
    }
}

// ---- hop: wave = 1 dst node; lane = (slot 0..7, c 0..7).
// One dwordx4 wave-load gathers 8 full 128 B rows (8 edges). Self edge virtual
// at k==e. 2-deep software pipeline keeps gathers in flight. ----
template <int HOP2>
__global__ void __launch_bounds__(256) hop_kernel(const int* __restrict__ offs,
                                                  const int* __restrict__ ends,
                                                  const int* __restrict__ adj,
                                                  const float* __restrict__ dinv,
                                                  const _Float16* __restrict__ xs,
                                                  _Float16* __restrict__ xs_next,
                                                  const float* __restrict__ bias,
                                                  float* __restrict__ out, int N) {
    int t = threadIdx.x;
    int n = blockIdx.x * 4 + (t >> 6);
    if (n >= N) return;
    int lane = t & 63;
    int slot = lane >> 3;     // edge slot 0..7
    int c = lane & 7;         // 16 B chunk: cols 8c..8c+7
    int b = offs[n], e = ends[n];
    const char* xsb = (const char*)xs;
    float one = 1.0f;
    float a0 = 0.f, a1 = 0.f, a2 = 0.f, a3 = 0.f,
          a4 = 0.f, a5 = 0.f, a6 = 0.f, a7 = 0.f;

    for (int kb = b; kb <= e; kb += 64) {    // <= e: virtual self edge at k==e
        int idx = kb + lane;
        int av = (idx < e) ? adj[idx] : 0;
        int nj = (min(63, e - kb) >> 3) + 1; // 1..8 sub-iterations of 8 edges

        int k0 = kb + slot;
        int ae0 = __shfl(av, slot);
        int r0 = (k0 < e) ? ae0 : ((k0 == e) ? n : NN);
        uint4 cur = *(const uint4*)(xsb + ((size_t)r0 << 7) + (c << 4));

        for (int j = 0; j < nj - 1; ++j) {
            int k = kb + ((j + 1) << 3) + slot;
            int ae = __shfl(av, ((j + 1) << 3) + slot);
            int r = (k < e) ? ae : ((k == e) ? n : NN);
            uint4 nxt = *(const uint4*)(xsb + ((size_t)r << 7) + (c << 4));
            MIX_LO(a0, cur.x, one); MIX_HI(a1, cur.x, one);
            MIX_LO(a2, cur.y, one); MIX_HI(a3, cur.y, one);
            MIX_LO(a4, cur.z, one); MIX_HI(a5, cur.z, one);
            MIX_LO(a6, cur.w, one); MIX_HI(a7, cur.w, one);
            cur = nxt;
        }
        MIX_LO(a0, cur.x, one); MIX_HI(a1, cur.x, one);
        MIX_LO(a2, cur.y, one); MIX_HI(a3, cur.y, one);
        MIX_LO(a4, cur.z, one); MIX_HI(a5, cur.z, one);
        MIX_LO(a6, cur.w, one); MIX_HI(a7, cur.w, one);
    }

    // reduce across the 8 slots (lane bits 3..5)
#pragma unroll
    for (int off = 8; off <= 32; off <<= 1) {
        a0 += __shfl_xor(a0, off); a1 += __shfl_xor(a1, off);
        a2 += __shfl_xor(a2, off); a3 += __shfl_xor(a3, off);
        a4 += __shfl_xor(a4, off); a5 += __shfl_xor(a5, off);
        a6 += __shfl_xor(a6, off); a7 += __shfl_xor(a7, off);
    }

    if (!HOP2) {
        if (slot == 0) {
            float d = dinv[n];
            float dd = d * d;
            uint4 wv;
            wv.x = pack16(a0 * dd, a1 * dd);
            wv.y = pack16(a2 * dd, a3 * dd);
            wv.z = pack16(a4 * dd, a5 * dd);
            wv.w = pack16(a6 * dd, a7 * dd);
            *(uint4*)((char*)xs_next + ((size_t)n << 7) + (c << 4)) = wv;
        }
    } else {
        float d = dinv[n];
        int col0 = 8 * c;
        bool act = col0 < F_OUT;            // c < 5
        float4 b0 = {0.f,0.f,0.f,0.f}, b1 = b0;
        if (act) {
            b0 = ((const float4*)bias)[2 * c];
            b1 = ((const float4*)bias)[2 * c + 1];
        }
        float l0 = a0 * d + b0.x, l1 = a1 * d + b0.y;
        float l2 = a2 * d + b0.z, l3 = a3 * d + b0.w;
        float l4 = a4 * d + b1.x, l5 = a5 * d + b1.y;
        float l6 = a6 * d + b1.z, l7 = a7 * d + b1.w;
        float vm = -INFINITY;
        if (act) {
            vm = fmaxf(fmaxf(fmaxf(l0, l1), fmaxf(l2, l3)),
                       fmaxf(fmaxf(l4, l5), fmaxf(l6, l7)));
        }
#pragma unroll
        for (int off = 1; off <= 4; off <<= 1) vm = fmaxf(vm, __shfl_xor(vm, off));
        float ex = 0.f;
        if (act) {
            ex = expf(l0 - vm) + expf(l1 - vm) + expf(l2 - vm) + expf(l3 - vm)
               + expf(l4 - vm) + expf(l5 - vm) + expf(l6 - vm) + expf(l7 - vm);
        }
#pragma unroll
        for (int off = 1; off <= 4; off <<= 1) ex += __shfl_xor(ex, off);
        if (slot == 0 && act) {
            float ls = vm + logf(ex);
            float4 o0 = {l0 - ls, l1 - ls, l2 - ls, l3 - ls};
            float4 o1 = {l4 - ls, l5 - ls, l6 - ls, l7 - ls};
            float* op = out + (size_t)n * F_OUT + col0;
            *(float4*)op = o0;
            *(float4*)(op + 4) = o1;
        }
    }
}

extern "C" void kernel_launch(void* const* d_in, const int* in_sizes, int n_in,
                              void* d_out, int out_size, void* d_ws, size_t ws_size,
                              hipStream_t stream) {
    const float* x    = (const float*)d_in[0];
    const int*   eidx = (const int*)d_in[1];
    const float* w    = (const float*)d_in[2];
    const float* bias = (const float*)d_in[3];
    float* out = (float*)d_out;

    const int E = in_sizes[1] / 2;
    const int N = NN;

    char* ws = (char*)d_ws;
    int*      bcount  = (int*)ws;      ws += 256 * 4;
    int*      bbase   = (int*)ws;      ws += 256 * 4;
    int*      bcursor = (int*)ws;      ws += 256 * 4;
    int*      offs    = (int*)ws;      ws += (size_t)N * 4;
    int*      ends    = (int*)ws;      ws += (size_t)N * 4;
    float*    dinv    = (float*)ws;    ws += (size_t)N * 4;
    int*      adj     = (int*)ws;      ws += (size_t)E * 4;
    _Float16* xs1     = (_Float16*)ws; ws += (size_t)(N + 1) * FH_PAD * 2;
    _Float16* xs2     = (_Float16*)ws; ws += (size_t)(N + 1) * FH_PAD * 2;
    int*      staged  = (int*)ws;

    const int* row = eidx;
    const int* col = eidx + E;

    hipMemsetAsync(bcount, 0, NBUCK * sizeof(int), stream);
    zrow_kernel<<<1, 64, 0, stream>>>(xs1, xs2);
    bhist_kernel<<<(E + EPB_A - 1) / EPB_A, 1024, 0, stream>>>(col, bcount, E);
    bscan_kernel<<<1, 256, 0, stream>>>(bcount, bbase, bcursor);
    part_kernel<<<(E + EPB_C - 1) / EPB_C, 1024, 0, stream>>>(row, col, bcursor, staged, E);
    build_kernel<<<NBUCK, 1024, 0, stream>>>(staged, bbase, adj, offs, ends, dinv, N, E);

    gemm_kernel<<<(N + 63) / 64, 256, 0, stream>>>(x, w, dinv, xs1, N);

    hop_kernel<0><<<(N + 3) / 4, 256, 0, stream>>>(offs, ends, adj, dinv, xs1, xs2,
                                                   bias, out, N);
    hop_kernel<1><<<(N + 3) / 4, 256, 0, stream>>>(offs, ends, adj, dinv, xs2, nullptr,
                                                   bias, out, N);
}

// Round 10
// 148.515 us; speedup vs baseline: 6.0790x; 1.1658x over previous
//
#include <hip/hip_runtime.h>
#include <math.h>

#define NN 100000
#define F_IN 128
#define F_OUT 40
#define FH_PAD 64       // fp16 row stride: 64 elems = 128 B = 8 x 16B chunks
#define BSHIFT 9        // 512 nodes per bucket
#define BSIZE (1 << BSHIFT)
#define NBUCK ((NN + BSIZE - 1) >> BSHIFT)   // 196
#define CAP 12288       // padded adj slots per bucket (exp ~10.6k, 13-sigma margin)
#define EPB_A 4096
#define EPB_C 16384

typedef short bf16x8 __attribute__((ext_vector_type(8)));
typedef float f32x4 __attribute__((ext_vector_type(4)));

__device__ __forceinline__ short f2bf(float f) {
    union { float f; unsigned u; } uf; uf.f = f;
    unsigned r = uf.u + 0x7FFF + ((uf.u >> 16) & 1);   // RNE
    return (short)(r >> 16);
}

__device__ __forceinline__ unsigned pack16(float x, float y) {
    union { _Float16 h; unsigned short s; } a, b;
    a.h = (_Float16)x; b.h = (_Float16)y;
    return (unsigned)a.s | ((unsigned)b.s << 16);
}

// f32 acc += f16 (lo or hi half of dword) -- one v_fma_mix_f32 each
#define MIX_LO(acc, d, one) \
    asm("v_fma_mix_f32 %0, %1, %2, %0 op_sel:[0,0,0] op_sel_hi:[1,0,0]" \
        : "+v"(acc) : "v"(d), "v"(one))
#define MIX_HI(acc, d, one) \
    asm("v_fma_mix_f32 %0, %1, %2, %0 op_sel:[1,0,0] op_sel_hi:[1,0,0]" \
        : "+v"(acc) : "v"(d), "v"(one))
#define MIX8(q) do { \
    MIX_LO(a0, q.x, one); MIX_HI(a1, q.x, one); \
    MIX_LO(a2, q.y, one); MIX_HI(a3, q.y, one); \
    MIX_LO(a4, q.z, one); MIX_HI(a5, q.z, one); \
    MIX_LO(a6, q.w, one); MIX_HI(a7, q.w, one); } while (0)

// ---- phase A: bucket histogram ----
__global__ void bhist_kernel(const int* __restrict__ col, int* __restrict__ bcount, int E) {
    __shared__ int h[NBUCK];
    for (int i = threadIdx.x; i < NBUCK; i += blockDim.x) h[i] = 0;
    __syncthreads();
    int e0 = blockIdx.x * EPB_A;
    int e1 = min(e0 + EPB_A, E);
    for (int e = e0 + threadIdx.x; e < e1; e += blockDim.x)
        atomicAdd(&h[col[e] >> BSHIFT], 1);
    __syncthreads();
    for (int i = threadIdx.x; i < NBUCK; i += blockDim.x)
        if (h[i]) atomicAdd(&bcount[i], h[i]);
}

// ---- phase B: scan bucket counts -> bbase; init bcursor ----
__global__ void bscan_kernel(const int* __restrict__ bcount, int* __restrict__ bbase,
                             int* __restrict__ bcursor) {
    __shared__ int sh[256];
    int i = threadIdx.x;
    int v = (i < NBUCK) ? bcount[i] : 0;
    sh[i] = v;
    __syncthreads();
    for (int off = 1; off < 256; off <<= 1) {
        int t = (i >= off) ? sh[i - off] : 0;
        __syncthreads();
        sh[i] += t;
        __syncthreads();
    }
    if (i < NBUCK) { int b = sh[i] - v; bbase[i] = b; bcursor[i] = b; }
}

// ---- phase C: partition edges; staged packs (c_local<<17)|row ----
__global__ void part_kernel(const int* __restrict__ row, const int* __restrict__ col,
                            int* __restrict__ bcursor, int* __restrict__ staged, int E) {
    __shared__ int h[NBUCK];
    __shared__ int cur[NBUCK];
    for (int i = threadIdx.x; i < NBUCK; i += blockDim.x) h[i] = 0;
    __syncthreads();
    int e0 = blockIdx.x * EPB_C;
    int e1 = min(e0 + EPB_C, E);
    for (int e = e0 + threadIdx.x; e < e1; e += blockDim.x)
        atomicAdd(&h[col[e] >> BSHIFT], 1);
    __syncthreads();
    for (int i = threadIdx.x; i < NBUCK; i += blockDim.x)
        cur[i] = h[i] ? atomicAdd(&bcursor[i], h[i]) : 0;
    __syncthreads();
    for (int e = e0 + threadIdx.x; e < e1; e += blockDim.x) {
        int c = col[e];
        int pos = atomicAdd(&cur[c >> BSHIFT], 1);
        staged[pos] = ((c & (BSIZE - 1)) << 17) | row[e];
    }
}

// ---- phase D: padded per-bucket CSR. Segment per node: [self, edges..., NN pads]
// length pad4(deg+1), pair-equalized so nodes (2i,2i+1) have equal L. ----
__global__ void __launch_bounds__(512) build_kernel(const int* __restrict__ staged,
                                                    const int* __restrict__ bbase,
                                                    int* __restrict__ adj,
                                                    int* __restrict__ offs,
                                                    float* __restrict__ dinv, int N, int E) {
    __shared__ int hist[BSIZE];
    __shared__ int lenp[BSIZE];
    __shared__ int cur[BSIZE];
    int bk = blockIdx.x;
    int node0 = bk << BSHIFT;
    int ebase = bbase[bk];
    int eend = (bk + 1 < NBUCK) ? bbase[bk + 1] : E;
    int i = threadIdx.x;          // 512 threads == BSIZE
    hist[i] = 0;
    __syncthreads();
    for (int e = ebase + i; e < eend; e += 512)
        atomicAdd(&hist[staged[e] >> 17], 1);
    __syncthreads();
    int v = hist[i];
    int Lp = (v + 1 + 3) & ~3;    // self + pad to mult of 4
    lenp[i] = Lp;
    __syncthreads();
    int LL = max(Lp, lenp[i ^ 1]);  // pair-equalize
    __syncthreads();
    lenp[i] = LL;
    __syncthreads();
    for (int off = 1; off < 512; off <<= 1) {   // inclusive scan
        int t = (i >= off) ? lenp[i - off] : 0;
        __syncthreads();
        lenp[i] += t;
        __syncthreads();
    }
    int excl = lenp[i] - LL;
    int gbase = bk * CAP;
    int n = node0 + i;
    if (n < N) {
        offs[n] = gbase + excl;
        dinv[n] = rsqrtf((float)v + 1.0f);
        adj[gbase + excl] = n;                       // self edge first
        for (int p = excl + 1 + v; p < excl + LL; ++p)
            adj[gbase + p] = NN;                     // pads -> zeroed dummy row
    }
    cur[i] = excl + 1;
    __syncthreads();
    for (int e = ebase + i; e < eend; e += 512) {
        int sv = staged[e];
        int pos = atomicAdd(&cur[sv >> 17], 1);
        adj[gbase + pos] = sv & 0x1FFFF;
    }
}

// ---- zero the dummy rows xs1[NN], xs2[NN] ----
__global__ void zrow_kernel(_Float16* xs1, _Float16* xs2) {
    int t = threadIdx.x;
    if (t < 32) ((unsigned*)xs1)[(size_t)NN * 32 + t] = 0u;
    else        ((unsigned*)xs2)[(size_t)NN * 32 + (t - 32)] = 0u;
}

// ---- MFMA gemm: xs1[n][j] = (x[n] . W[:,j]) * dinv[n]; fp16 out, full 64-col row ----
__global__ void __launch_bounds__(256) gemm_kernel(const float* __restrict__ x,
                                                   const float* __restrict__ w,
                                                   const float* __restrict__ dinv,
                                                   _Float16* __restrict__ xs1, int N) {
    __shared__ bf16x8 shB[3][4][64];
    int t = threadIdx.x;
    for (int idx = t; idx < 3 * 4 * 64; idx += 256) {
        int lane = idx & 63;
        int ks = (idx >> 6) & 3;
        int jt = idx >> 8;
        int j = 16 * jt + (lane & 15);
        int k0 = 32 * ks + 8 * (lane >> 4);
        bf16x8 v;
#pragma unroll
        for (int i = 0; i < 8; ++i)
            v[i] = (j < F_OUT) ? f2bf(w[(k0 + i) * F_OUT + j]) : (short)0;
        shB[jt][ks][lane] = v;
    }
    __syncthreads();
    int wave = t >> 6, lane = t & 63;
    int node0 = blockIdx.x * 64 + wave * 16;
    if (node0 >= N) return;

    const float* xrow = x + (size_t)(node0 + (lane & 15)) * F_IN + 8 * (lane >> 4);
    f32x4 acc0 = {0.f, 0.f, 0.f, 0.f};
    f32x4 acc1 = acc0, acc2 = acc0;
#pragma unroll
    for (int ks = 0; ks < 4; ++ks) {
        float4 lo = *(const float4*)(xrow + 32 * ks);
        float4 hi = *(const float4*)(xrow + 32 * ks + 4);
        bf16x8 a;
        a[0] = f2bf(lo.x); a[1] = f2bf(lo.y); a[2] = f2bf(lo.z); a[3] = f2bf(lo.w);
        a[4] = f2bf(hi.x); a[5] = f2bf(hi.y); a[6] = f2bf(hi.z); a[7] = f2bf(hi.w);
        acc0 = __builtin_amdgcn_mfma_f32_16x16x32_bf16(a, shB[0][ks][lane], acc0, 0, 0, 0);
        acc1 = __builtin_amdgcn_mfma_f32_16x16x32_bf16(a, shB[1][ks][lane], acc1, 0, 0, 0);
        acc2 = __builtin_amdgcn_mfma_f32_16x16x32_bf16(a, shB[2][ks][lane], acc2, 0, 0, 0);
    }
    int colj = lane & 15;
    int rbase = (lane >> 4) * 4;
#pragma unroll
    for (int r = 0; r < 4; ++r) {
        int node = node0 + rbase + r;
        float d = dinv[node];
        _Float16* dst = xs1 + (size_t)node * FH_PAD;
        dst[colj]      = (_Float16)(acc0[r] * d);
        dst[16 + colj] = (_Float16)(acc1[r] * d);
        dst[32 + colj] = (colj < 8) ? (_Float16)(acc2[r] * d) : (_Float16)0.f;
        dst[48 + colj] = (_Float16)0.f;
    }
}

// ---- hop: wave = 2 nodes (pair); lane = (node, slot 0..3, c 0..7).
// adj segments pre-padded (self first, NN pads, pair-equal L) -> pure stream:
// no bounds logic, no virtual self. 8 edges (4+4) per dwordx4 gather. ----
template <int HOP2>
__global__ void __launch_bounds__(256) hop_kernel(const int* __restrict__ offs,
                                                  const float* __restrict__ dinv,
                                                  const int* __restrict__ adj,
                                                  const _Float16* __restrict__ xs,
                                                  _Float16* __restrict__ xs_next,
                                                  const float* __restrict__ bias,
                                                  float* __restrict__ out) {
    int t = threadIdx.x;
    int wave = t >> 6, lane = t & 63;
    int n0 = blockIdx.x * 8 + wave * 2;
    int node = lane >> 5;
    int slot = (lane >> 3) & 3;
    int c = lane & 7;
    int o0 = offs[n0], o1 = offs[n0 + 1];
    int L = o1 - o0;              // pair-equal padded length
    int nj = L >> 2;              // sub-iterations (4 edges/node each)
    int b = node ? o1 : o0;
    int n = n0 + node;
    const char* xsb = (const char*)xs;
    float one = 1.0f;
    float a0 = 0.f, a1 = 0.f, a2 = 0.f, a3 = 0.f,
          a4 = 0.f, a5 = 0.f, a6 = 0.f, a7 = 0.f;
    int coff = c << 4;
    int bw = (node << 5) | slot;  // bperm source-lane base

    for (int done = 0, tw = 0; done < nj; done += 8, ++tw) {
        int av = adj[b + (tw << 5) + (lane & 31)];
        int cnt = min(8, nj - done);
        int r = __shfl(av, bw);
        uint4 cur = *(const uint4*)(xsb + ((size_t)(unsigned)r << 7) + coff);
        for (int j = 1; j < cnt; ++j) {
            int r2 = __shfl(av, bw + (j << 2));
            uint4 nxt = *(const uint4*)(xsb + ((size_t)(unsigned)r2 << 7) + coff);
            MIX8(cur);
            cur = nxt;
        }
        MIX8(cur);
    }

    // slot reduce: 2 levels (slots stride 8 within each node's 32 lanes)
#pragma unroll
    for (int off = 8; off <= 16; off <<= 1) {
        a0 += __shfl_xor(a0, off); a1 += __shfl_xor(a1, off);
        a2 += __shfl_xor(a2, off); a3 += __shfl_xor(a3, off);
        a4 += __shfl_xor(a4, off); a5 += __shfl_xor(a5, off);
        a6 += __shfl_xor(a6, off); a7 += __shfl_xor(a7, off);
    }

    if (!HOP2) {
        if (slot == 0) {
            float d = dinv[n];
            float dd = d * d;
            uint4 wv;
            wv.x = pack16(a0 * dd, a1 * dd);
            wv.y = pack16(a2 * dd, a3 * dd);
            wv.z = pack16(a4 * dd, a5 * dd);
            wv.w = pack16(a6 * dd, a7 * dd);
            *(uint4*)((char*)xs_next + ((size_t)n << 7) + coff) = wv;
        }
    } else {
        float d = dinv[n];
        int col0 = 8 * c;
        bool act = col0 < F_OUT;            // c < 5
        float4 b0 = {0.f, 0.f, 0.f, 0.f}, b1 = b0;
        if (act) {
            b0 = ((const float4*)bias)[2 * c];
            b1 = ((const float4*)bias)[2 * c + 1];
        }
        float l0 = a0 * d + b0.x, l1 = a1 * d + b0.y;
        float l2 = a2 * d + b0.z, l3 = a3 * d + b0.w;
        float l4 = a4 * d + b1.x, l5 = a5 * d + b1.y;
        float l6 = a6 * d + b1.z, l7 = a7 * d + b1.w;
        float vm = -INFINITY;
        if (act)
            vm = fmaxf(fmaxf(fmaxf(l0, l1), fmaxf(l2, l3)),
                       fmaxf(fmaxf(l4, l5), fmaxf(l6, l7)));
#pragma unroll
        for (int off = 1; off <= 4; off <<= 1) vm = fmaxf(vm, __shfl_xor(vm, off));
        const float R = 1.44269504089f;     // 1/ln2
        float ex = 0.f;
        if (act)
            ex = exp2f((l0 - vm) * R) + exp2f((l1 - vm) * R)
               + exp2f((l2 - vm) * R) + exp2f((l3 - vm) * R)
               + exp2f((l4 - vm) * R) + exp2f((l5 - vm) * R)
               + exp2f((l6 - vm) * R) + exp2f((l7 - vm) * R);
#pragma unroll
        for (int off = 1; off <= 4; off <<= 1) ex += __shfl_xor(ex, off);
        if (slot == 0 && act) {
            float ls = vm + 0.69314718056f * log2f(ex);
            float4 q0 = {l0 - ls, l1 - ls, l2 - ls, l3 - ls};
            float4 q1 = {l4 - ls, l5 - ls, l6 - ls, l7 - ls};
            float* op = out + (size_t)n * F_OUT + col0;
            *(float4*)op = q0;
            *(float4*)(op + 4) = q1;
        }
    }
}

extern "C" void kernel_launch(void* const* d_in, const int* in_sizes, int n_in,
                              void* d_out, int out_size, void* d_ws, size_t ws_size,
                              hipStream_t stream) {
    const float* x    = (const float*)d_in[0];
    const int*   eidx = (const int*)d_in[1];
    const float* w    = (const float*)d_in[2];
    const float* bias = (const float*)d_in[3];
    float* out = (float*)d_out;

    const int E = in_sizes[1] / 2;
    const int N = NN;

    char* ws = (char*)d_ws;
    int*      bcount  = (int*)ws;      ws += 256 * 4;
    int*      bbase   = (int*)ws;      ws += 256 * 4;
    int*      bcursor = (int*)ws;      ws += 256 * 4;
    int*      offs    = (int*)ws;      ws += (size_t)N * 4;
    float*    dinv    = (float*)ws;    ws += (size_t)N * 4;
    int*      adj     = (int*)ws;      ws += (size_t)NBUCK * CAP * 4;   // 9.6 MB padded
    _Float16* xs1     = (_Float16*)ws; ws += (size_t)(N + 1) * FH_PAD * 2;
    _Float16* xs2     = (_Float16*)ws; ws += (size_t)(N + 1) * FH_PAD * 2;
    int*      staged  = (int*)ws;

    const int* row = eidx;
    const int* col = eidx + E;

    hipMemsetAsync(bcount, 0, NBUCK * sizeof(int), stream);
    zrow_kernel<<<1, 64, 0, stream>>>(xs1, xs2);
    bhist_kernel<<<(E + EPB_A - 1) / EPB_A, 1024, 0, stream>>>(col, bcount, E);
    bscan_kernel<<<1, 256, 0, stream>>>(bcount, bbase, bcursor);
    part_kernel<<<(E + EPB_C - 1) / EPB_C, 1024, 0, stream>>>(row, col, bcursor, staged, E);
    build_kernel<<<NBUCK, 512, 0, stream>>>(staged, bbase, adj, offs, dinv, N, E);

    gemm_kernel<<<(N + 63) / 64, 256, 0, stream>>>(x, w, dinv, xs1, N);

    hop_kernel<0><<<N / 8, 256, 0, stream>>>(offs, dinv, adj, xs1, xs2, bias, out);
    hop_kernel<1><<<N / 8, 256, 0, stream>>>(offs, dinv, adj, xs2, nullptr, bias, out);
}

// Round 11
// 132.288 us; speedup vs baseline: 6.8246x; 1.1227x over previous
//
#include <hip/hip_runtime.h>
#include <math.h>

#define NN 100000
#define F_IN 128
#define F_OUT 40
#define FH_PAD 64       // fp16 row stride: 64 elems = 128 B = 8 x 16B chunks
#define BSHIFT 9        // 512 nodes per bucket
#define BSIZE (1 << BSHIFT)
#define NBUCK ((NN + BSIZE - 1) >> BSHIFT)   // 196
#define SCAP 12288      // staged slots per bucket (mean 8192, sigma 90)
#define CAP 14336       // padded adj slots per bucket (quad-equalized ~11.6k)
#define EPB_C 16384

typedef short bf16x8 __attribute__((ext_vector_type(8)));
typedef float f32x4 __attribute__((ext_vector_type(4)));
typedef _Float16 h2 __attribute__((ext_vector_type(2)));

union U4H { uint4 u; h2 h[4]; };

__device__ __forceinline__ short f2bf(float f) {
    union { float f; unsigned u; } uf; uf.f = f;
    unsigned r = uf.u + 0x7FFF + ((uf.u >> 16) & 1);   // RNE
    return (short)(r >> 16);
}

__device__ __forceinline__ unsigned pack16(float x, float y) {
    union { _Float16 h; unsigned short s; } a, b;
    a.h = (_Float16)x; b.h = (_Float16)y;
    return (unsigned)a.s | ((unsigned)b.s << 16);
}

__device__ __forceinline__ h2 shfl_xor_h2(h2 v, int m) {
    int x = __builtin_bit_cast(int, v);
    x = __shfl_xor(x, m);
    return __builtin_bit_cast(h2, x);
}

// ---- setup: bcursor[bk]=bk*SCAP; zero dummy rows xs1[NN], xs2[NN] ----
__global__ void setup_kernel(int* __restrict__ bcursor, _Float16* xs1, _Float16* xs2) {
    int t = threadIdx.x;
    if (t < NBUCK) bcursor[t] = t * SCAP;
    if (t < 32) ((unsigned*)xs1)[(size_t)NN * 32 + t] = 0u;
    else if (t < 64) ((unsigned*)xs2)[(size_t)NN * 32 + (t - 32)] = 0u;
}

// ---- partition edges into fixed per-bucket staged regions; packs (c_local<<17)|row ----
__global__ void part_kernel(const int* __restrict__ row, const int* __restrict__ col,
                            int* __restrict__ bcursor, int* __restrict__ staged, int E) {
    __shared__ int h[NBUCK];
    __shared__ int cur[NBUCK];
    for (int i = threadIdx.x; i < NBUCK; i += blockDim.x) h[i] = 0;
    __syncthreads();
    int e0 = blockIdx.x * EPB_C;
    int e1 = min(e0 + EPB_C, E);
    for (int e = e0 + threadIdx.x; e < e1; e += blockDim.x)
        atomicAdd(&h[col[e] >> BSHIFT], 1);
    __syncthreads();
    for (int i = threadIdx.x; i < NBUCK; i += blockDim.x)
        cur[i] = h[i] ? atomicAdd(&bcursor[i], h[i]) : 0;
    __syncthreads();
    for (int e = e0 + threadIdx.x; e < e1; e += blockDim.x) {
        int c = col[e];
        int pos = atomicAdd(&cur[c >> BSHIFT], 1);
        staged[pos] = ((c & (BSIZE - 1)) << 17) | row[e];
    }
}

// ---- padded per-bucket CSR. Segment per node: [self, edges..., NN pads],
// length pad2(deg+1), quad-equalized (nodes 4i..4i+3 share L). Wave-shfl scan. ----
__global__ void __launch_bounds__(512) build_kernel(const int* __restrict__ staged,
                                                    const int* __restrict__ bcursor,
                                                    int* __restrict__ adj,
                                                    int* __restrict__ offs,
                                                    float* __restrict__ dinv, int N) {
    __shared__ int hist[BSIZE];
    __shared__ int cur[BSIZE];
    __shared__ int wsum[8];
    int bk = blockIdx.x;
    int node0 = bk << BSHIFT;
    int sbase = bk * SCAP;
    int send = bcursor[bk];           // sbase + count
    int gbase = bk * CAP;
    int i = threadIdx.x;              // 512 threads == BSIZE
    hist[i] = 0;
    __syncthreads();
    for (int e = sbase + i; e < send; e += 512)
        atomicAdd(&hist[staged[e] >> 17], 1);
    __syncthreads();
    int v = hist[i];
    int Lp = (v + 2) & ~1;            // self + pad to even
    int L1 = max(Lp, __shfl_xor(Lp, 1));
    int LL = max(L1, __shfl_xor(L1, 2));   // quad-equalized
    // wave-level inclusive scan of LL
    int lane = i & 63, w = i >> 6;
    int x = LL;
#pragma unroll
    for (int d = 1; d < 64; d <<= 1) {
        int y = __shfl_up(x, d, 64);
        if (lane >= d) x += y;
    }
    if (lane == 63) wsum[w] = x;
    __syncthreads();
    int wpre = 0;
    for (int k = 0; k < w; ++k) wpre += wsum[k];
    int excl = wpre + x - LL;
    int n = node0 + i;
    if (n < N) {
        offs[n] = gbase + excl;
        dinv[n] = rsqrtf((float)v + 1.0f);
        adj[gbase + excl] = n;                        // self edge first
        for (int p = excl + 1 + v; p < excl + LL; ++p)
            adj[gbase + p] = NN;                      // pads -> zeroed dummy row
    }
    cur[i] = excl + 1;
    __syncthreads();
    for (int e = sbase + i; e < send; e += 512) {
        int sv = staged[e];
        int pos = atomicAdd(&cur[sv >> 17], 1);
        adj[gbase + pos] = sv & 0x1FFFF;
    }
}

// ---- MFMA gemm: xs1[n][j] = (x[n] . W[:,j]) * dinv[n]; fp16 out, full 64-col row ----
__global__ void __launch_bounds__(256) gemm_kernel(const float* __restrict__ x,
                                                   const float* __restrict__ w,
                                                   const float* __restrict__ dinv,
                                                   _Float16* __restrict__ xs1, int N) {
    __shared__ bf16x8 shB[3][4][64];
    int t = threadIdx.x;
    for (int idx = t; idx < 3 * 4 * 64; idx += 256) {
        int lane = idx & 63;
        int ks = (idx >> 6) & 3;
        int jt = idx >> 8;
        int j = 16 * jt + (lane & 15);
        int k0 = 32 * ks + 8 * (lane >> 4);
        bf16x8 v;
#pragma unroll
        for (int i = 0; i < 8; ++i)
            v[i] = (j < F_OUT) ? f2bf(w[(k0 + i) * F_OUT + j]) : (short)0;
        shB[jt][ks][lane] = v;
    }
    __syncthreads();
    int wave = t >> 6, lane = t & 63;
    int node0 = blockIdx.x * 64 + wave * 16;
    if (node0 >= N) return;

    const float* xrow = x + (size_t)(node0 + (lane & 15)) * F_IN + 8 * (lane >> 4);
    f32x4 acc0 = {0.f, 0.f, 0.f, 0.f};
    f32x4 acc1 = acc0, acc2 = acc0;
#pragma unroll
    for (int ks = 0; ks < 4; ++ks) {
        float4 lo = *(const float4*)(xrow + 32 * ks);
        float4 hi = *(const float4*)(xrow + 32 * ks + 4);
        bf16x8 a;
        a[0] = f2bf(lo.x); a[1] = f2bf(lo.y); a[2] = f2bf(lo.z); a[3] = f2bf(lo.w);
        a[4] = f2bf(hi.x); a[5] = f2bf(hi.y); a[6] = f2bf(hi.z); a[7] = f2bf(hi.w);
        acc0 = __builtin_amdgcn_mfma_f32_16x16x32_bf16(a, shB[0][ks][lane], acc0, 0, 0, 0);
        acc1 = __builtin_amdgcn_mfma_f32_16x16x32_bf16(a, shB[1][ks][lane], acc1, 0, 0, 0);
        acc2 = __builtin_amdgcn_mfma_f32_16x16x32_bf16(a, shB[2][ks][lane], acc2, 0, 0, 0);
    }
    int colj = lane & 15;
    int rbase = (lane >> 4) * 4;
#pragma unroll
    for (int r = 0; r < 4; ++r) {
        int node = node0 + rbase + r;
        float d = dinv[node];
        _Float16* dst = xs1 + (size_t)node * FH_PAD;
        dst[colj]      = (_Float16)(acc0[r] * d);
        dst[16 + colj] = (_Float16)(acc1[r] * d);
        dst[32 + colj] = (colj < 8) ? (_Float16)(acc2[r] * d) : (_Float16)0.f;
        dst[48 + colj] = (_Float16)0.f;
    }
}

// ---- hop: wave = 4 nodes; lane = (node 0..3, slot 0..1, c 0..7).
// Segments pre-padded (self first, pads, quad-equal L): pure stream, no bounds
// logic. 8 edges per dwordx4 gather; packed-f16 accumulate (v_pk_add_f16). ----
template <int HOP2>
__global__ void __launch_bounds__(256) hop_kernel(const int* __restrict__ offs,
                                                  const float* __restrict__ dinv,
                                                  const int* __restrict__ adj,
                                                  const _Float16* __restrict__ xs,
                                                  _Float16* __restrict__ xs_next,
                                                  const float* __restrict__ bias,
                                                  float* __restrict__ out) {
    int t = threadIdx.x;
    int wave = t >> 6, lane = t & 63;
    int n0 = blockIdx.x * 16 + wave * 4;
    int node = lane >> 4;
    int slot = (lane >> 3) & 1;
    int c = lane & 7;
    int n = n0 + node;
    int obase = offs[n];                       // per-lane: own node's segment base
    int L = offs[n0 + 1] - offs[n0];           // quad-equal padded length
    int nj = L >> 1;                           // j-iters (2 edges/node each)
    const char* xsb = (const char*)xs;
    int coff = c << 4;
    int bw = (node << 4) | slot;               // shfl source-lane base

    h2 A0 = {0.f, 0.f}, A1 = A0, A2 = A0, A3 = A0;
#define ACC4(q) do { A0 += q.h[0]; A1 += q.h[1]; A2 += q.h[2]; A3 += q.h[3]; } while (0)

    int li = lane & 15;
    int av0 = adj[obase + li];
    int av1 = adj[obase + 16 + li];            // may over-read; unused lanes only
    int r0 = __shfl(av0, bw);
    U4H curv; curv.u = *(const uint4*)(xsb + ((size_t)(unsigned)r0 << 7) + coff);
    int jg = 1;
    int jcap = min(nj, 16);
    for (; jg < jcap; ++jg) {
        int av = (jg & 8) ? av1 : av0;
        int r2 = __shfl(av, bw + ((jg & 7) << 1));
        U4H nxt; nxt.u = *(const uint4*)(xsb + ((size_t)(unsigned)r2 << 7) + coff);
        ACC4(curv);
        curv = nxt;
    }
    for (; jg < nj; ++jg) {                    // rare: deg > 30
        if ((jg & 7) == 0) av1 = adj[obase + ((jg >> 3) << 4) + li];
        int r2 = __shfl(av1, bw + ((jg & 7) << 1));
        U4H nxt; nxt.u = *(const uint4*)(xsb + ((size_t)(unsigned)r2 << 7) + coff);
        ACC4(curv);
        curv = nxt;
    }
    ACC4(curv);

    // reduce across the 2 slots (lane bit 3), packed
    A0 += shfl_xor_h2(A0, 8);
    A1 += shfl_xor_h2(A1, 8);
    A2 += shfl_xor_h2(A2, 8);
    A3 += shfl_xor_h2(A3, 8);

    float f0 = (float)A0[0], f1 = (float)A0[1];
    float f2 = (float)A1[0], f3 = (float)A1[1];
    float f4 = (float)A2[0], f5 = (float)A2[1];
    float f6 = (float)A3[0], f7 = (float)A3[1];

    if (!HOP2) {
        if (slot == 0) {
            float d = dinv[n];
            float dd = d * d;
            uint4 wv;
            wv.x = pack16(f0 * dd, f1 * dd);
            wv.y = pack16(f2 * dd, f3 * dd);
            wv.z = pack16(f4 * dd, f5 * dd);
            wv.w = pack16(f6 * dd, f7 * dd);
            *(uint4*)((char*)xs_next + ((size_t)n << 7) + coff) = wv;
        }
    } else {
        float d = dinv[n];
        int col0 = 8 * c;
        bool act = col0 < F_OUT;               // c < 5
        float4 b0 = {0.f, 0.f, 0.f, 0.f}, b1 = b0;
        if (act) {
            b0 = ((const float4*)bias)[2 * c];
            b1 = ((const float4*)bias)[2 * c + 1];
        }
        float l0 = f0 * d + b0.x, l1 = f1 * d + b0.y;
        float l2 = f2 * d + b0.z, l3 = f3 * d + b0.w;
        float l4 = f4 * d + b1.x, l5 = f5 * d + b1.y;
        float l6 = f6 * d + b1.z, l7 = f7 * d + b1.w;
        float vm = -INFINITY;
        if (act)
            vm = fmaxf(fmaxf(fmaxf(l0, l1), fmaxf(l2, l3)),
                       fmaxf(fmaxf(l4, l5), fmaxf(l6, l7)));
#pragma unroll
        for (int off = 1; off <= 4; off <<= 1) vm = fmaxf(vm, __shfl_xor(vm, off));
        const float R = 1.44269504089f;        // 1/ln2
        float ex = 0.f;
        if (act)
            ex = exp2f((l0 - vm) * R) + exp2f((l1 - vm) * R)
               + exp2f((l2 - vm) * R) + exp2f((l3 - vm) * R)
               + exp2f((l4 - vm) * R) + exp2f((l5 - vm) * R)
               + exp2f((l6 - vm) * R) + exp2f((l7 - vm) * R);
#pragma unroll
        for (int off = 1; off <= 4; off <<= 1) ex += __shfl_xor(ex, off);
        if (slot == 0 && act) {
            float ls = vm + 0.69314718056f * log2f(ex);
            float4 q0 = {l0 - ls, l1 - ls, l2 - ls, l3 - ls};
            float4 q1 = {l4 - ls, l5 - ls, l6 - ls, l7 - ls};
            float* op = out + (size_t)n * F_OUT + col0;
            *(float4*)op = q0;
            *(float4*)(op + 4) = q1;
        }
    }
#undef ACC4
}

extern "C" void kernel_launch(void* const* d_in, const int* in_sizes, int n_in,
                              void* d_out, int out_size, void* d_ws, size_t ws_size,
                              hipStream_t stream) {
    const float* x    = (const float*)d_in[0];
    const int*   eidx = (const int*)d_in[1];
    const float* w    = (const float*)d_in[2];
    const float* bias = (const float*)d_in[3];
    float* out = (float*)d_out;

    const int E = in_sizes[1] / 2;
    const int N = NN;

    char* ws = (char*)d_ws;
    int*      bcursor = (int*)ws;      ws += 256 * 4;
    int*      offs    = (int*)ws;      ws += (size_t)N * 4;
    float*    dinv    = (float*)ws;    ws += (size_t)N * 4;
    int*      adj     = (int*)ws;      ws += (size_t)NBUCK * CAP * 4;    // 11.2 MB
    _Float16* xs1     = (_Float16*)ws; ws += (size_t)(N + 1) * FH_PAD * 2;
    _Float16* xs2     = (_Float16*)ws; ws += (size_t)(N + 1) * FH_PAD * 2;
    int*      staged  = (int*)ws;      // NBUCK*SCAP ints = 9.6 MB

    const int* row = eidx;
    const int* col = eidx + E;

    setup_kernel<<<1, 256, 0, stream>>>(bcursor, xs1, xs2);
    part_kernel<<<(E + EPB_C - 1) / EPB_C, 1024, 0, stream>>>(row, col, bcursor, staged, E);
    build_kernel<<<NBUCK, 512, 0, stream>>>(staged, bcursor, adj, offs, dinv, N);

    gemm_kernel<<<(N + 63) / 64, 256, 0, stream>>>(x, w, dinv, xs1, N);

    hop_kernel<0><<<N / 16, 256, 0, stream>>>(offs, dinv, adj, xs1, xs2, bias, out);
    hop_kernel<1><<<N / 16, 256, 0, stream>>>(offs, dinv, adj, xs2, nullptr, bias, out);
}

// Round 12
// 130.562 us; speedup vs baseline: 6.9148x; 1.0132x over previous
//
#include <hip/hip_runtime.h>
#include <math.h>

#define NN 100000
#define F_IN 128
#define F_OUT 40
#define BSHIFT 9        // 512 nodes per bucket
#define BSIZE (1 << BSHIFT)
#define NBUCK ((NN + BSIZE - 1) >> BSHIFT)   // 196
#define SCAP 12288      // staged slots per bucket
#define CAP 14336       // padded adj slots per bucket
#define EPB_C 16384
// split feature layout: A = cols 0..31 (64 B rows), B = cols 32..39 (16 B rows)
#define OFFB  ((unsigned)((NN + 1) * 64))        // 6,400,064 : start of B block
#define ADUM  ((unsigned)(NN * 64))              // A dummy row (zeros)
#define XSBYTES ((size_t)8000128)                // (N+1)*80 rounded up

typedef short bf16x8 __attribute__((ext_vector_type(8)));
typedef float f32x4 __attribute__((ext_vector_type(4)));
typedef _Float16 h2 __attribute__((ext_vector_type(2)));

union U4H { uint4 u; h2 h[4]; };

__device__ __forceinline__ short f2bf(float f) {
    union { float f; unsigned u; } uf; uf.f = f;
    unsigned r = uf.u + 0x7FFF + ((uf.u >> 16) & 1);   // RNE
    return (short)(r >> 16);
}

__device__ __forceinline__ unsigned pack16(float x, float y) {
    union { _Float16 h; unsigned short s; } a, b;
    a.h = (_Float16)x; b.h = (_Float16)y;
    return (unsigned)a.s | ((unsigned)b.s << 16);
}

__device__ __forceinline__ h2 shfl_h2(h2 v, int src) {
    int x = __builtin_bit_cast(int, v);
    x = __shfl(x, src);
    return __builtin_bit_cast(h2, x);
}

// ---- setup: bcursor[bk]=bk*SCAP; zero dummy rows (A + B) in both buffers ----
__global__ void setup_kernel(int* __restrict__ bcursor, char* xs1, char* xs2) {
    int t = threadIdx.x;
    if (t < NBUCK) bcursor[t] = t * SCAP;
    if (t < 16)      *(unsigned*)(xs1 + ADUM + t * 4) = 0u;
    else if (t < 20) *(unsigned*)(xs1 + OFFB + (size_t)NN * 16 + (t - 16) * 4) = 0u;
    else if (t < 36) *(unsigned*)(xs2 + ADUM + (t - 20) * 4) = 0u;
    else if (t < 40) *(unsigned*)(xs2 + OFFB + (size_t)NN * 16 + (t - 36) * 4) = 0u;
}

// ---- partition edges into fixed per-bucket staged regions; packs (c_local<<17)|row ----
__global__ void part_kernel(const int* __restrict__ row, const int* __restrict__ col,
                            int* __restrict__ bcursor, int* __restrict__ staged, int E) {
    __shared__ int h[NBUCK];
    __shared__ int cur[NBUCK];
    for (int i = threadIdx.x; i < NBUCK; i += blockDim.x) h[i] = 0;
    __syncthreads();
    int e0 = blockIdx.x * EPB_C;
    int e1 = min(e0 + EPB_C, E);
    for (int e = e0 + threadIdx.x; e < e1; e += blockDim.x)
        atomicAdd(&h[col[e] >> BSHIFT], 1);
    __syncthreads();
    for (int i = threadIdx.x; i < NBUCK; i += blockDim.x)
        cur[i] = h[i] ? atomicAdd(&bcursor[i], h[i]) : 0;
    __syncthreads();
    for (int e = e0 + threadIdx.x; e < e1; e += blockDim.x) {
        int c = col[e];
        int pos = atomicAdd(&cur[c >> BSHIFT], 1);
        staged[pos] = ((c & (BSIZE - 1)) << 17) | row[e];
    }
}

// ---- padded per-bucket CSR. Segment: [self, edges..., NN pads], length pad3(deg+1),
// quad-equalized. Wave-shfl scan. ----
__global__ void __launch_bounds__(512) build_kernel(const int* __restrict__ staged,
                                                    const int* __restrict__ bcursor,
                                                    int* __restrict__ adj,
                                                    int* __restrict__ offs,
                                                    float* __restrict__ dinv, int N) {
    __shared__ int hist[BSIZE];
    __shared__ int cur[BSIZE];
    __shared__ int wsum[8];
    int bk = blockIdx.x;
    int node0 = bk << BSHIFT;
    int sbase = bk * SCAP;
    int send = bcursor[bk];
    int gbase = bk * CAP;
    int i = threadIdx.x;
    hist[i] = 0;
    __syncthreads();
    for (int e = sbase + i; e < send; e += 512)
        atomicAdd(&hist[staged[e] >> 17], 1);
    __syncthreads();
    int v = hist[i];
    int Lp = ((v + 3) / 3) * 3;            // pad3(deg+1)
    int L1 = max(Lp, __shfl_xor(Lp, 1));
    int LL = max(L1, __shfl_xor(L1, 2));   // quad-equalized
    int lane = i & 63, w = i >> 6;
    int x = LL;
#pragma unroll
    for (int d = 1; d < 64; d <<= 1) {
        int y = __shfl_up(x, d, 64);
        if (lane >= d) x += y;
    }
    if (lane == 63) wsum[w] = x;
    __syncthreads();
    int wpre = 0;
    for (int k = 0; k < w; ++k) wpre += wsum[k];
    int excl = wpre + x - LL;
    int n = node0 + i;
    if (n < N) {
        offs[n] = gbase + excl;
        dinv[n] = rsqrtf((float)v + 1.0f);
        adj[gbase + excl] = n;                        // self edge first
        for (int p = excl + 1 + v; p < excl + LL; ++p)
            adj[gbase + p] = NN;                      // pads -> dummy row
    }
    cur[i] = excl + 1;
    __syncthreads();
    for (int e = sbase + i; e < send; e += 512) {
        int sv = staged[e];
        int pos = atomicAdd(&cur[sv >> 17], 1);
        adj[gbase + pos] = sv & 0x1FFFF;
    }
}

// ---- MFMA gemm: xs1[n] = (x[n] . W) * dinv[n]; fp16, split A/B layout ----
__global__ void __launch_bounds__(256) gemm_kernel(const float* __restrict__ x,
                                                   const float* __restrict__ w,
                                                   const float* __restrict__ dinv,
                                                   char* __restrict__ xsb, int N) {
    __shared__ bf16x8 shB[3][4][64];
    int t = threadIdx.x;
    for (int idx = t; idx < 3 * 4 * 64; idx += 256) {
        int lane = idx & 63;
        int ks = (idx >> 6) & 3;
        int jt = idx >> 8;
        int j = 16 * jt + (lane & 15);
        int k0 = 32 * ks + 8 * (lane >> 4);
        bf16x8 v;
#pragma unroll
        for (int i = 0; i < 8; ++i)
            v[i] = (j < F_OUT) ? f2bf(w[(k0 + i) * F_OUT + j]) : (short)0;
        shB[jt][ks][lane] = v;
    }
    __syncthreads();
    int wave = t >> 6, lane = t & 63;
    int node0 = blockIdx.x * 64 + wave * 16;
    if (node0 >= N) return;

    const float* xrow = x + (size_t)(node0 + (lane & 15)) * F_IN + 8 * (lane >> 4);
    f32x4 acc0 = {0.f, 0.f, 0.f, 0.f};
    f32x4 acc1 = acc0, acc2 = acc0;
#pragma unroll
    for (int ks = 0; ks < 4; ++ks) {
        float4 lo = *(const float4*)(xrow + 32 * ks);
        float4 hi = *(const float4*)(xrow + 32 * ks + 4);
        bf16x8 a;
        a[0] = f2bf(lo.x); a[1] = f2bf(lo.y); a[2] = f2bf(lo.z); a[3] = f2bf(lo.w);
        a[4] = f2bf(hi.x); a[5] = f2bf(hi.y); a[6] = f2bf(hi.z); a[7] = f2bf(hi.w);
        acc0 = __builtin_amdgcn_mfma_f32_16x16x32_bf16(a, shB[0][ks][lane], acc0, 0, 0, 0);
        acc1 = __builtin_amdgcn_mfma_f32_16x16x32_bf16(a, shB[1][ks][lane], acc1, 0, 0, 0);
        acc2 = __builtin_amdgcn_mfma_f32_16x16x32_bf16(a, shB[2][ks][lane], acc2, 0, 0, 0);
    }
    int colj = lane & 15;
    int rbase = (lane >> 4) * 4;
#pragma unroll
    for (int r = 0; r < 4; ++r) {
        int node = node0 + rbase + r;
        float d = dinv[node];
        _Float16* dstA = (_Float16*)(xsb + (size_t)node * 64);
        dstA[colj]      = (_Float16)(acc0[r] * d);
        dstA[16 + colj] = (_Float16)(acc1[r] * d);
        if (colj < 8)
            ((_Float16*)(xsb + OFFB + (size_t)node * 16))[colj] = (_Float16)(acc2[r] * d);
    }
}

// ---- hop: wave = 4 nodes; lane = (node, sub 0..15). sub<15: edge slot s=sub/5,
// chunk q=sub%5 (q<4 -> A 16B chunk q, q==4 -> B 16B). lane 15: stride-0 dummy.
// 12 edges per wave gather; packed-f16 accumulate; bpermute slot-reduce. ----
template <int HOP2>
__global__ void __launch_bounds__(256) hop_kernel(const int* __restrict__ offs,
                                                  const float* __restrict__ dinv,
                                                  const int* __restrict__ adj,
                                                  const char* __restrict__ src,
                                                  char* __restrict__ dst,
                                                  const float* __restrict__ bias,
                                                  float* __restrict__ out) {
    int t = threadIdx.x;
    int wave = t >> 6, lane = t & 63;
    int n0 = blockIdx.x * 16 + wave * 4;
    int node = lane >> 4;
    int sub = lane & 15;
    int n = n0 + node;
    int s = sub / 5;                 // 0..3 (3 only for sub==15)
    int q = sub - s * 5;             // 0..4
    bool padl = (sub == 15);
    unsigned strideB = padl ? 0u : (q == 4 ? 16u : 64u);
    unsigned cstB    = padl ? ADUM : (q == 4 ? OFFB : (unsigned)(q * 16));

    int obase = offs[n];
    int L = offs[n0 + 1] - offs[n0];      // quad-equal
    int nj = L / 3;

    h2 A0 = {0.f, 0.f}, A1 = A0, A2 = A0, A3 = A0;
#define ACC4(qq) do { A0 += qq.h[0]; A1 += qq.h[1]; A2 += qq.h[2]; A3 += qq.h[3]; } while (0)

    int r = adj[obase + s];
    U4H cur; cur.u = *(const uint4*)(src + (unsigned)r * strideB + cstB);
    for (int j = 1; j < nj; ++j) {
        int r2 = adj[obase + j * 3 + s];
        U4H nxt; nxt.u = *(const uint4*)(src + (unsigned)r2 * strideB + cstB);
        ACC4(cur);
        cur = nxt;
    }
    ACC4(cur);
#undef ACC4

    // reduce across the 3 edge slots: lanes sub, sub+5, sub+10 (mod 15) share q
    int nb = lane & 0x30;
    int i1 = nb | ((sub + 5) % 15);
    int i2 = nb | ((sub + 10) % 15);
    A0 = A0 + shfl_h2(A0, i1) + shfl_h2(A0, i2);
    A1 = A1 + shfl_h2(A1, i1) + shfl_h2(A1, i2);
    A2 = A2 + shfl_h2(A2, i1) + shfl_h2(A2, i2);
    A3 = A3 + shfl_h2(A3, i1) + shfl_h2(A3, i2);

    float f0 = (float)A0[0], f1 = (float)A0[1];
    float f2 = (float)A1[0], f3 = (float)A1[1];
    float f4 = (float)A2[0], f5 = (float)A2[1];
    float f6 = (float)A3[0], f7 = (float)A3[1];

    if (!HOP2) {
        if (sub < 5) {
            float d = dinv[n];
            float dd = d * d;
            uint4 wv;
            wv.x = pack16(f0 * dd, f1 * dd);
            wv.y = pack16(f2 * dd, f3 * dd);
            wv.z = pack16(f4 * dd, f5 * dd);
            wv.w = pack16(f6 * dd, f7 * dd);
            *(uint4*)(dst + (unsigned)n * strideB + cstB) = wv;
        }
    } else {
        float d = dinv[n];
        float4 b0 = ((const float4*)bias)[2 * q];
        float4 b1 = ((const float4*)bias)[2 * q + 1];
        float l0 = f0 * d + b0.x, l1 = f1 * d + b0.y;
        float l2 = f2 * d + b0.z, l3 = f3 * d + b0.w;
        float l4 = f4 * d + b1.x, l5 = f5 * d + b1.y;
        float l6 = f6 * d + b1.z, l7 = f7 * d + b1.w;
        float mp = fmaxf(fmaxf(fmaxf(l0, l1), fmaxf(l2, l3)),
                         fmaxf(fmaxf(l4, l5), fmaxf(l6, l7)));
        float m = mp;
#pragma unroll
        for (int dd = 1; dd <= 4; ++dd)
            m = fmaxf(m, __shfl(mp, nb | ((sub + dd) % 5)));
        const float R = 1.44269504089f;
        float sp = exp2f((l0 - m) * R) + exp2f((l1 - m) * R)
                 + exp2f((l2 - m) * R) + exp2f((l3 - m) * R)
                 + exp2f((l4 - m) * R) + exp2f((l5 - m) * R)
                 + exp2f((l6 - m) * R) + exp2f((l7 - m) * R);
        float sx = sp;
#pragma unroll
        for (int dd = 1; dd <= 4; ++dd)
            sx += __shfl(sp, nb | ((sub + dd) % 5));
        if (sub < 5) {
            float ls = m + 0.69314718056f * log2f(sx);
            float4 q0 = {l0 - ls, l1 - ls, l2 - ls, l3 - ls};
            float4 q1 = {l4 - ls, l5 - ls, l6 - ls, l7 - ls};
            float* op = out + (size_t)n * F_OUT + 8 * q;
            *(float4*)op = q0;
            *(float4*)(op + 4) = q1;
        }
    }
}

extern "C" void kernel_launch(void* const* d_in, const int* in_sizes, int n_in,
                              void* d_out, int out_size, void* d_ws, size_t ws_size,
                              hipStream_t stream) {
    const float* x    = (const float*)d_in[0];
    const int*   eidx = (const int*)d_in[1];
    const float* w    = (const float*)d_in[2];
    const float* bias = (const float*)d_in[3];
    float* out = (float*)d_out;

    const int E = in_sizes[1] / 2;
    const int N = NN;

    char* ws = (char*)d_ws;
    int*   bcursor = (int*)ws;   ws += 256 * 4;
    int*   offs    = (int*)ws;   ws += (size_t)N * 4;
    float* dinv    = (float*)ws; ws += (size_t)N * 4;
    int*   adj     = (int*)ws;   ws += (size_t)NBUCK * CAP * 4;   // 11.2 MB
    char*  xs1     = ws;         ws += XSBYTES;                   // 8.0 MB (A+B)
    char*  xs2     = ws;         ws += XSBYTES;
    int*   staged  = (int*)ws;                                    // 9.6 MB

    const int* row = eidx;
    const int* col = eidx + E;

    setup_kernel<<<1, 256, 0, stream>>>(bcursor, xs1, xs2);
    part_kernel<<<(E + EPB_C - 1) / EPB_C, 1024, 0, stream>>>(row, col, bcursor, staged, E);
    build_kernel<<<NBUCK, 512, 0, stream>>>(staged, bcursor, adj, offs, dinv, N);

    gemm_kernel<<<(N + 63) / 64, 256, 0, stream>>>(x, w, dinv, xs1, N);

    hop_kernel<0><<<N / 16, 256, 0, stream>>>(offs, dinv, adj, xs1, xs2, bias, out);
    hop_kernel<1><<<N / 16, 256, 0, stream>>>(offs, dinv, adj, xs2, nullptr, bias, out);
}